// Round 17
// baseline (187.869 us; speedup 1.0000x reference)
//
#include <hip/hip_runtime.h>

typedef unsigned short u16;
typedef __attribute__((ext_vector_type(8))) unsigned short ushort8;
typedef __attribute__((ext_vector_type(8))) short bf16x8;
typedef __attribute__((ext_vector_type(4))) float f32x4;

#define DEVINL __device__ __forceinline__

DEVINL float bf2f(u16 u){ union{unsigned i; float f;} v; v.i = ((unsigned)u) << 16; return v.f; }
DEVINL u16 f2bf(float f){
  unsigned x = __builtin_bit_cast(unsigned, f);
  x += 0x7fffu + ((x >> 16) & 1u);
  return (u16)(x >> 16);
}
DEVINL void gl_lds16(const void* g, void* l){
  __builtin_amdgcn_global_load_lds((const __attribute__((address_space(1))) unsigned*)g,
                                   (__attribute__((address_space(3))) unsigned*)l, 16, 0, 0);
}
template<int N> DEVINL void wait_vmcnt(){
  asm volatile("s_waitcnt vmcnt(%0)" :: "n"(N) : "memory");
}
DEVINL void hard_barrier(){
  asm volatile("" ::: "memory");
  __builtin_amdgcn_s_barrier();
  asm volatile("" ::: "memory");
}
DEVINL float wsum(float v){
  #pragma unroll
  for (int o = 32; o; o >>= 1) v += __shfl_xor(v, o, 64);
  return v;
}

// ------- weights f32->bf16 (blocks 0..511) + QKV biases f32 copy (block 512) -------
__global__ __launch_bounds__(256) void cvt4b_k(const float* __restrict__ s0, const float* __restrict__ s1,
                 const float* __restrict__ s2, const float* __restrict__ s3,
                 const float* __restrict__ bq, const float* __restrict__ bk, const float* __restrict__ bv,
                 u16* __restrict__ wdst, float* __restrict__ bdst){
  if (blockIdx.x == 512){
    for (int j = threadIdx.x; j < 1536; j += 256)
      bdst[j] = (j < 512) ? bq[j] : (j < 1024) ? bk[j-512] : bv[j-1024];
    return;
  }
  const int g = blockIdx.x >> 7;
  const float* src = (g==0) ? s0 : (g==1) ? s1 : (g==2) ? s2 : s3;
  const int i = ((blockIdx.x & 127)*256 + threadIdx.x)*8;
  float4 f0 = *(const float4*)(src + i);
  float4 f1 = *(const float4*)(src + i + 4);
  ushort8 o;
  o[0]=f2bf(f0.x); o[1]=f2bf(f0.y); o[2]=f2bf(f0.z); o[3]=f2bf(f0.w);
  o[4]=f2bf(f1.x); o[5]=f2bf(f1.y); o[6]=f2bf(f1.z); o[7]=f2bf(f1.w);
  *(ushort8*)(wdst + g*262144 + i) = o;
}

// ------- sum 4 bf16 partials, normalize by per-row sum of the 64 psum slices -------
__global__ __launch_bounds__(256) void reduce4_k(const u16* __restrict__ part,
                 const float* __restrict__ psum, u16* __restrict__ dst){
  __shared__ float invsh[4];
  const int t = threadIdx.x, w = t>>6, ln = t&63;
  const int row = blockIdx.x*4 + w;
  float s = psum[ln*8192 + blockIdx.y*4096 + row];
  s = wsum(s);
  if (ln == 0) invsh[w] = 1.f / s;
  __syncthreads();
  const int i = (blockIdx.x*256 + t)*8;
  const u16* p = part + (size_t)blockIdx.y*8388608;
  float a[8] = {};
  #pragma unroll
  for (int ks = 0; ks < 4; ++ks){
    ushort8 u = *(const ushort8*)(p + (size_t)ks*2097152 + i);
    #pragma unroll
    for (int j = 0; j < 8; ++j) a[j] += bf2f(u[j]);
  }
  const float iv = invsh[w];
  ushort8 o;
  #pragma unroll
  for (int j = 0; j < 8; ++j) o[j] = f2bf(a[j] * iv);
  *(ushort8*)(dst + (size_t)blockIdx.y*2097152 + i) = o;
}

// ---------------- GroupNorm ----------------
__global__ __launch_bounds__(256) void gn_stats_k(const float* __restrict__ x, float* __restrict__ stats){
  __shared__ __align__(16) float red[8];
  const float* px = x + ((size_t)blockIdx.x << 16);
  const int t = threadIdx.x;
  float s = 0.f, ss = 0.f;
  for (int off = t*4; off < 65536; off += 1024){
    float4 u = *(const float4*)(px + off);
    s  += u.x + u.y + u.z + u.w;
    ss += u.x*u.x + u.y*u.y + u.z*u.z + u.w*u.w;
  }
  s = wsum(s); ss = wsum(ss);
  if ((t & 63) == 0){ red[t>>6] = s; red[4+(t>>6)] = ss; }
  __syncthreads();
  if (t == 0){
    float S1 = red[0]+red[1]+red[2]+red[3];
    float S2 = red[4]+red[5]+red[6]+red[7];
    float mean = S1 * (1.f/65536.f);
    float var  = S2 * (1.f/65536.f) - mean*mean;
    stats[2*blockIdx.x]   = mean;
    stats[2*blockIdx.x+1] = rsqrtf(var + 1e-6f);
  }
}

__global__ __launch_bounds__(256) void gn_apply_k(const float* __restrict__ x, const float* __restrict__ gamma,
                 const float* __restrict__ beta, const float* __restrict__ stats, u16* __restrict__ ht){
  __shared__ __align__(16) u16 tile[32*512];
  const int b = blockIdx.y, n0 = blockIdx.x*32, t = threadIdx.x;
  #pragma unroll
  for (int it = 0; it < 8; ++it){
    int c  = it*64 + (t>>2);
    int nn = (t&3)*8;
    const float* px = x + ((size_t)(b*512 + c) << 12) + n0 + nn;
    float4 u0 = *(const float4*)(px);
    float4 u1 = *(const float4*)(px + 4);
    float mean = stats[2*(b*32 + (c>>4))];
    float rstd = stats[2*(b*32 + (c>>4)) + 1];
    float ga = gamma[c], be = beta[c];
    float f[8] = {u0.x,u0.y,u0.z,u0.w,u1.x,u1.y,u1.z,u1.w};
    #pragma unroll
    for (int j = 0; j < 8; ++j)
      tile[(nn+j)*512 + c] = f2bf((f[j] - mean) * rstd * ga + be);
  }
  __syncthreads();
  const int rw = t>>3, sg = t&7;
  #pragma unroll
  for (int uu = 0; uu < 8; ++uu){
    ushort8 v = *(const ushort8*)(tile + rw*512 + sg*64 + uu*8);
    *(ushort8*)(ht + ((size_t)(b*4096 + n0 + rw) << 9) + sg*64 + uu*8) = v;
  }
}

// ============ 256x256 NT GEMM, ring-4 + register double-buffer ============
// Iter u: STAGE(u+3) | LDreg(u+1)->next | MFMA32(cur) | vmcnt(8) | barrier.
// Register loads for u+1 issue BEFORE MFMA(u) -> read latency hides under MFMA.
// No in-loop vmcnt(0); counted waits keep 2 units in flight across barriers.
// EXPSUM: epilogue stores exp(acc); per-wave 64-col row sums -> psum (deterministic).
template<bool EXPSUM>
__global__ __launch_bounds__(512) void gemm8_nt(
    const u16* __restrict__ A, const u16* __restrict__ Bt, u16* __restrict__ C,
    float* __restrict__ psum,
    int K, int lda, int ldb, int ldc, int zdiv,
    long long aStrB, long long aStr, long long bStrB, long long bStr,
    long long cStrB, long long cStr)
{
  extern __shared__ __align__(16) char smem[];   // 131072: A 4x16K @0 | B 4x16K @65536
  const int z = blockIdx.z, z1 = z / zdiv, z2 = z % zdiv;
  A  += (size_t)aStrB*z1 + (size_t)aStr*z2;
  Bt += (size_t)bStrB*z1 + (size_t)bStr*z2;
  C  += (size_t)cStrB*z1 + (size_t)cStr*z2;
  const int nwg = gridDim.x*gridDim.y;
  int wg = blockIdx.y*gridDim.x + blockIdx.x;
  wg = (wg & 7)*(nwg >> 3) + (wg >> 3);
  const int m0 = (wg / gridDim.x)*256, n0 = (wg % gridDim.x)*256;

  const int t = threadIdx.x, wv = t>>6, ln = t&63;
  const int wm = wv>>2, wn = wv&3;
  const int lq = ln&15, lg = ln>>4;
  const int srow = ln>>2;
  const int sseg = (((ln&3) ^ ((srow>>1)&3)))*8;   // swizzled source seg (per-lane const)
  const int rslot = (lg ^ ((lq>>1)&3))*16;         // swizzled read slot (per-lane const)

  // unit u covers k in [u*32, u*32+32); A slot (u&3)*16K, B at +65536
  auto STAGE_A = [&](int u){
    char* base = smem + (u&3)*16384 + wv*1024;
    const u16* g = A + (size_t)(m0 + wv*16 + srow)*lda + u*32 + sseg;
    gl_lds16(g, base);
    gl_lds16(g + (size_t)128*lda, base + 8192);
  };
  auto STAGE_B = [&](int u){
    char* base = smem + 65536 + (u&3)*16384 + wv*1024;
    const u16* g = Bt + (size_t)(n0 + wv*16 + srow)*ldb + u*32 + sseg;
    gl_lds16(g, base);
    gl_lds16(g + (size_t)128*ldb, base + 8192);
  };
  auto LDA8 = [&](int u, bf16x8* a){
    const char* p = smem + (u&3)*16384 + (wm*128 + lq)*64 + rslot;
    #pragma unroll
    for (int i = 0; i < 8; ++i) a[i] = *(const bf16x8*)(p + i*1024);
  };
  auto LDB4 = [&](int u, bf16x8* b){
    const char* p = smem + 65536 + (u&3)*16384 + (wn*64 + lq)*64 + rslot;
    #pragma unroll
    for (int j = 0; j < 4; ++j) b[j] = *(const bf16x8*)(p + j*1024);
  };

  f32x4 acc[8][4] = {};
  auto MFMA32 = [&](bf16x8* a8, bf16x8* b4){
    __builtin_amdgcn_s_setprio(1);
    #pragma unroll
    for (int n = 0; n < 4; ++n)
      #pragma unroll
      for (int m = 0; m < 8; ++m)
        acc[m][n] = __builtin_amdgcn_mfma_f32_16x16x32_bf16(a8[m], b4[n], acc[m][n], 0, 0, 0);
    __builtin_amdgcn_s_setprio(0);
  };

  bf16x8 aC[8], bC[4], aN[8], bN[4];
  // prologue: prime units 0,1,2 (24 loads); land 0,1; load regs(0)
  STAGE_A(0); STAGE_B(0); STAGE_A(1); STAGE_B(1); STAGE_A(2); STAGE_B(2);
  wait_vmcnt<8>();
  hard_barrier();
  LDA8(0, aC); LDB4(0, bC);
  const int U = K >> 5;   // multiple of 2, >= 16
  for (int u = 0; u < U; u += 2){
    // ---- even: cur = C ----
    if (u+3 < U){ STAGE_A(u+3); STAGE_B(u+3); }
    if (u+1 < U){ LDA8(u+1, aN); LDB4(u+1, bN); }
    MFMA32(aC, bC);
    if (u+3 < U) wait_vmcnt<8>(); else wait_vmcnt<0>();
    hard_barrier();
    // ---- odd: cur = N ----
    const int v = u + 1;
    if (v+3 < U){ STAGE_A(v+3); STAGE_B(v+3); }
    if (v+1 < U){ LDA8(v+1, aC); LDB4(v+1, bC); }
    MFMA32(aN, bN);
    if (v+3 < U) wait_vmcnt<8>(); else wait_vmcnt<0>();
    hard_barrier();
  }
  // epilogue: C/D layout col=lane&15, row=(lane>>4)*4+reg
  const int slice = EXPSUM ? ((n0 >> 8)*4 + wn) : 0;
  #pragma unroll
  for (int m = 0; m < 8; ++m)
    #pragma unroll
    for (int r2 = 0; r2 < 4; ++r2){
      const int mg = m0 + wm*128 + m*16 + lg*4 + r2;
      u16* cp = C + (size_t)mg*ldc + n0 + wn*64 + lq;
      if constexpr (EXPSUM){
        float e[4], rs = 0.f;
        #pragma unroll
        for (int n = 0; n < 4; ++n){ e[n] = __expf(acc[m][n][r2]); rs += e[n]; }
        rs += __shfl_xor(rs, 1, 64);
        rs += __shfl_xor(rs, 2, 64);
        rs += __shfl_xor(rs, 4, 64);
        rs += __shfl_xor(rs, 8, 64);
        if (lq == 0) psum[slice*8192 + z1*4096 + mg] = rs;
        #pragma unroll
        for (int n = 0; n < 4; ++n) cp[n*16] = f2bf(e[n]);
      } else {
        #pragma unroll
        for (int n = 0; n < 4; ++n) cp[n*16] = f2bf(acc[m][n][r2]);
      }
    }
}

// ------- fused Q/K/V projection: grid (32,4,6), z = mat*2 + batch -------
__global__ __launch_bounds__(256) void qkv_k(
    const u16* __restrict__ Wstk, const u16* __restrict__ ht,
    const float* __restrict__ biases, u16* __restrict__ dstBase)
{
  __shared__ __align__(16) char smem[32768];
  char* smA0 = smem;
  char* smA1 = smem + 8192;
  char* smB0 = smem + 16384;
  char* smB1 = smem + 24576;
  const int z = blockIdx.z, mat = z >> 1, b = z & 1;
  const u16* A  = Wstk + mat*262144;
  const u16* Bt = ht + (size_t)b*2097152;
  const float* bias = biases + mat*512;
  const float oscale = (mat == 0) ? 0.044194173824159216f : 1.0f;
  u16* dst = dstBase + (size_t)mat*4194304 + (size_t)b*2097152;
  const int m0 = blockIdx.y*128, n0 = blockIdx.x*128;
  const int t = threadIdx.x, wv = t>>6, ln = t&63;
  const int wm = wv>>1, wn = wv&1;
  const int lq = ln&15, lg = ln>>4;
  const int srow = ln>>2;
  const int sseg = (((ln&3) ^ ((srow>>1)&3)))*8;
  const int rslot = (lg ^ ((lq>>1)&3))*16;
  f32x4 acc[4][4] = {};
  for (int kk = 0; kk < 512; kk += 64){
    __syncthreads();
    #pragma unroll
    for (int r = 0; r < 2; ++r){
      const int rr = r*64 + wv*16;
      const u16* pa = A  + (size_t)(m0 + rr + srow)*512 + kk + sseg;
      const u16* pb = Bt + (size_t)(n0 + rr + srow)*512 + kk + sseg;
      gl_lds16(pa,      smA0 + rr*64);
      gl_lds16(pa + 32, smA1 + rr*64);
      gl_lds16(pb,      smB0 + rr*64);
      gl_lds16(pb + 32, smB1 + rr*64);
    }
    __syncthreads();
    #pragma unroll
    for (int half = 0; half < 2; ++half){
      const char* pA = half ? smA1 : smA0;
      const char* pB = half ? smB1 : smB0;
      bf16x8 af[4], bfv[4];
      #pragma unroll
      for (int i = 0; i < 4; ++i) af[i]  = *(const bf16x8*)(pA + ((wm*64 + i*16 + lq)<<6) + rslot);
      #pragma unroll
      for (int j = 0; j < 4; ++j) bfv[j] = *(const bf16x8*)(pB + ((wn*64 + j*16 + lq)<<6) + rslot);
      #pragma unroll
      for (int i = 0; i < 4; ++i)
        #pragma unroll
        for (int j = 0; j < 4; ++j)
          acc[i][j] = __builtin_amdgcn_mfma_f32_16x16x32_bf16(af[i], bfv[j], acc[i][j], 0, 0, 0);
    }
  }
  if (mat == 2){          // V: direct C[m][n], ldc=4096
    #pragma unroll
    for (int i = 0; i < 4; ++i)
      #pragma unroll
      for (int r2 = 0; r2 < 4; ++r2){
        const int mg = m0 + wm*64 + i*16 + lg*4 + r2;
        float bv = bias[mg];
        #pragma unroll
        for (int j = 0; j < 4; ++j){
          const int ng = n0 + wn*64 + j*16 + lq;
          dst[(size_t)mg*4096 + ng] = f2bf(acc[i][j][r2] + bv);
        }
      }
  } else {                // Q/K: transposed C^T[n][m], ldc=512
    __syncthreads();
    u16* ct = (u16*)smem;  // [128 n][128 m]
    #pragma unroll
    for (int i = 0; i < 4; ++i)
      #pragma unroll
      for (int j = 0; j < 4; ++j)
        #pragma unroll
        for (int r2 = 0; r2 < 4; ++r2){
          const int ml = wm*64 + i*16 + lg*4 + r2;
          const int nl = wn*64 + j*16 + lq;
          ct[nl*128 + ml] = f2bf((acc[i][j][r2] + bias[m0 + ml]) * oscale);
        }
    __syncthreads();
    const int rw = t>>1, hf = (t&1)*64;
    #pragma unroll
    for (int u = 0; u < 8; ++u){
      *(ushort8*)(dst + (size_t)(n0 + rw)*512 + m0 + hf + u*8) =
          *(const ushort8*)(ct + rw*128 + hf + u*8);
    }
  }
}

// ---------------- 128x128 NT GEMM (final projection) ----------------
template<bool TRANS_OUT, bool HAS_BIAS, bool HAS_RES, bool F32OUT>
__global__ __launch_bounds__(256) void gemm_nt(
    const u16* __restrict__ A, const u16* __restrict__ Bt,
    const float* __restrict__ bias, const float* __restrict__ res, void* __restrict__ Cw_,
    int K, int lda, int ldb, int ldc, int zdiv,
    long long aStrB, long long aStr, long long bStrB, long long bStr,
    long long cStrB, long long cStr, long long rStrB, float oscale)
{
  __shared__ __align__(16) char smem[32768];
  char* smA0 = smem;
  char* smA1 = smem + 8192;
  char* smB0 = smem + 16384;
  char* smB1 = smem + 24576;
  const int z = blockIdx.z;
  const int z1 = z / zdiv, z2 = z % zdiv;
  A  += (size_t)aStrB*z1 + (size_t)aStr*z2;
  Bt += (size_t)bStrB*z1 + (size_t)bStr*z2;
  u16*   Cw16 = (u16*)Cw_   + (size_t)cStrB*z1 + (size_t)cStr*z2;
  float* Cw32 = (float*)Cw_ + (size_t)cStrB*z1 + (size_t)cStr*z2;
  const float* resp = HAS_RES ? (res + (size_t)rStrB*z1) : nullptr;
  const int m0 = blockIdx.y*128, n0 = blockIdx.x*128;
  const int t = threadIdx.x, wv = t>>6, ln = t&63;
  const int wm = wv>>1, wn = wv&1;
  const int lq = ln&15, lg = ln>>4;
  const int srow = ln>>2;
  const int sseg = (((ln&3) ^ ((srow>>1)&3)))*8;
  const int rslot = (lg ^ ((lq>>1)&3))*16;
  f32x4 acc[4][4] = {};
  for (int kk = 0; kk < K; kk += 64){
    __syncthreads();
    #pragma unroll
    for (int r = 0; r < 2; ++r){
      const int rr = r*64 + wv*16;
      const u16* pa = A  + (size_t)(m0 + rr + srow)*lda + kk + sseg;
      const u16* pb = Bt + (size_t)(n0 + rr + srow)*ldb + kk + sseg;
      gl_lds16(pa,      smA0 + rr*64);
      gl_lds16(pa + 32, smA1 + rr*64);
      gl_lds16(pb,      smB0 + rr*64);
      gl_lds16(pb + 32, smB1 + rr*64);
    }
    __syncthreads();
    #pragma unroll
    for (int half = 0; half < 2; ++half){
      const char* pA = half ? smA1 : smA0;
      const char* pB = half ? smB1 : smB0;
      bf16x8 af[4], bfv[4];
      #pragma unroll
      for (int i = 0; i < 4; ++i) af[i]  = *(const bf16x8*)(pA + ((wm*64 + i*16 + lq)<<6) + rslot);
      #pragma unroll
      for (int j = 0; j < 4; ++j) bfv[j] = *(const bf16x8*)(pB + ((wn*64 + j*16 + lq)<<6) + rslot);
      #pragma unroll
      for (int i = 0; i < 4; ++i)
        #pragma unroll
        for (int j = 0; j < 4; ++j)
          acc[i][j] = __builtin_amdgcn_mfma_f32_16x16x32_bf16(af[i], bfv[j], acc[i][j], 0, 0, 0);
    }
  }
  if constexpr (!TRANS_OUT){
    #pragma unroll
    for (int i = 0; i < 4; ++i){
      #pragma unroll
      for (int r2 = 0; r2 < 4; ++r2){
        const int mg = m0 + wm*64 + i*16 + lg*4 + r2;
        float bv = HAS_BIAS ? bias[mg] : 0.f;
        #pragma unroll
        for (int j = 0; j < 4; ++j){
          const int ng = n0 + wn*64 + j*16 + lq;
          float v = (acc[i][j][r2] + bv) * oscale;
          if (HAS_RES) v += resp[(size_t)mg*ldc + ng];
          if constexpr (F32OUT) Cw32[(size_t)mg*ldc + ng] = v;
          else                  Cw16[(size_t)mg*ldc + ng] = f2bf(v);
        }
      }
    }
  } else {
    __syncthreads();
    u16* ct = (u16*)smem;
    #pragma unroll
    for (int i = 0; i < 4; ++i)
      #pragma unroll
      for (int j = 0; j < 4; ++j)
        #pragma unroll
        for (int r2 = 0; r2 < 4; ++r2){
          const int ml = wm*64 + i*16 + lg*4 + r2;
          const int nl = wn*64 + j*16 + lq;
          float v = acc[i][j][r2];
          if (HAS_BIAS) v += bias[m0 + ml];
          ct[nl*128 + ml] = f2bf(v * oscale);
        }
    __syncthreads();
    const int rw = t>>1, hf = (t&1)*64;
    #pragma unroll
    for (int u = 0; u < 8; ++u){
      *(ushort8*)(Cw16 + (size_t)(n0 + rw)*ldc + m0 + hf + u*8) =
          *(const ushort8*)(ct + rw*128 + hf + u*8);
    }
  }
}

// ---------------- launch ----------------
extern "C" void kernel_launch(void* const* d_in, const int* in_sizes, int n_in,
                              void* d_out, int out_size, void* d_ws, size_t ws_size,
                              hipStream_t stream)
{
  const float* x   = (const float*)d_in[0];
  const float* gam = (const float*)d_in[1];
  const float* bet = (const float*)d_in[2];
  const float* wq  = (const float*)d_in[3];
  const float* bq  = (const float*)d_in[4];
  const float* wk  = (const float*)d_in[5];
  const float* bk  = (const float*)d_in[6];
  const float* wvp = (const float*)d_in[7];
  const float* bv  = (const float*)d_in[8];
  const float* wo  = (const float*)d_in[9];
  const float* bo  = (const float*)d_in[10];
  float* out = (float*)d_out;

  // ws layout: stats | psum 2MB | biasQKV | W bf16 x4 | Qt|Kt|Vb|attT | Sbuf 64MB | part 32MB
  char* w = (char*)d_ws;
  float* stats   = (float*)w;
  float* psum    = (float*)(w + 4096);
  float* biasQKV = (float*)(w + 2134016);
  u16* wqb  = (u16*)(w + (size_t)4194304);
  u16* wob  = wqb + 3*262144;
  u16* Qt   = wqb + 4*262144;
  u16* Kt   = Qt + 4194304;
  u16* Vb   = Kt + 4194304;
  u16* attT = Vb + 4194304;
  u16* Sbuf = attT + 4194304;
  u16* part = Sbuf + 33554432;
  u16* ht   = (u16*)d_out;   // GN output lives in d_out until qkv done

  const long long NC = 4096LL*512, NN = 4096LL*4096;

  cvt4b_k<<<dim3(513), dim3(256), 0, stream>>>(wq, wk, wvp, wo, bq, bk, bv, wqb, biasQKV);
  gn_stats_k<<<dim3(64), dim3(256), 0, stream>>>(x, stats);
  gn_apply_k<<<dim3(128,2), dim3(256), 0, stream>>>(x, gam, bet, stats, ht);
  // fused Q/K/V projections (Qt pre-scaled by 512^-0.5)
  qkv_k<<<dim3(32,4,6), dim3(256), 0, stream>>>(wqb, ht, biasQKV, Qt);
  // expS[b][nq][nk] = exp(sum_c Qt[nq][c]*Kt[nk][c]); row partials -> psum
  gemm8_nt<true><<<dim3(16,16,2), dim3(512), 131072, stream>>>(
      Qt, Kt, Sbuf, psum, 512, 512, 512, 4096, 1, NC, 0, NC, 0, NN, 0);
  // split-K PV (4-way) on unnormalized expS
  gemm8_nt<false><<<dim3(2,16,8), dim3(512), 131072, stream>>>(
      Sbuf, Vb, part, nullptr, 1024, 4096, 4096, 512, 4,
      NN, 1024, NC, 1024, 8388608, 2097152);
  // sum partials + normalize (inv computed in-kernel from psum)
  reduce4_k<<<dim3(1024,2), dim3(256), 0, stream>>>(part, psum, attT);
  // out = x + (Wo att + bo)
  gemm_nt<false, true, true, true><<<dim3(32,4,2), dim3(256), 0, stream>>>(
      wob, attT, bo, x, out, 512, 512, 512, 4096, 1, 0,0, NC,0, NC,0, NC, 1.0f);
}

// Round 18
// 167.346 us; speedup vs baseline: 1.1226x; 1.1226x over previous
//
#include <hip/hip_runtime.h>

typedef unsigned short u16;
typedef __attribute__((ext_vector_type(8))) unsigned short ushort8;
typedef __attribute__((ext_vector_type(8))) short bf16x8;
typedef __attribute__((ext_vector_type(4))) float f32x4;

#define DEVINL __device__ __forceinline__

DEVINL float bf2f(u16 u){ union{unsigned i; float f;} v; v.i = ((unsigned)u) << 16; return v.f; }
DEVINL u16 f2bf(float f){
  unsigned x = __builtin_bit_cast(unsigned, f);
  x += 0x7fffu + ((x >> 16) & 1u);
  return (u16)(x >> 16);
}
DEVINL void gl_lds16(const void* g, void* l){
  __builtin_amdgcn_global_load_lds((const __attribute__((address_space(1))) unsigned*)g,
                                   (__attribute__((address_space(3))) unsigned*)l, 16, 0, 0);
}
template<int N> DEVINL void wait_vmcnt(){
  asm volatile("s_waitcnt vmcnt(%0)" :: "n"(N) : "memory");
}
DEVINL void hard_barrier(){
  asm volatile("" ::: "memory");
  __builtin_amdgcn_s_barrier();
  asm volatile("" ::: "memory");
}
DEVINL float wsum(float v){
  #pragma unroll
  for (int o = 32; o; o >>= 1) v += __shfl_xor(v, o, 64);
  return v;
}

// ------- prep: weights f32->bf16 (blocks 0..511), QKV biases (512), GN partial stats (513..768) -------
// psum2[grp][chunk][2]: grp = b*32+g (64), chunk = quarter of the group's 65536 f32.
__global__ __launch_bounds__(256) void prep_k(const float* __restrict__ s0, const float* __restrict__ s1,
                 const float* __restrict__ s2, const float* __restrict__ s3,
                 const float* __restrict__ bq, const float* __restrict__ bk, const float* __restrict__ bv,
                 const float* __restrict__ x,
                 u16* __restrict__ wdst, float* __restrict__ bdst, float* __restrict__ psum2){
  const int bx = blockIdx.x, t = threadIdx.x;
  if (bx < 512){
    const int g = bx >> 7;
    const float* src = (g==0) ? s0 : (g==1) ? s1 : (g==2) ? s2 : s3;
    const int i = ((bx & 127)*256 + t)*8;
    float4 f0 = *(const float4*)(src + i);
    float4 f1 = *(const float4*)(src + i + 4);
    ushort8 o;
    o[0]=f2bf(f0.x); o[1]=f2bf(f0.y); o[2]=f2bf(f0.z); o[3]=f2bf(f0.w);
    o[4]=f2bf(f1.x); o[5]=f2bf(f1.y); o[6]=f2bf(f1.z); o[7]=f2bf(f1.w);
    *(ushort8*)(wdst + g*262144 + i) = o;
    return;
  }
  if (bx == 512){
    for (int j = t; j < 1536; j += 256)
      bdst[j] = (j < 512) ? bq[j] : (j < 1024) ? bk[j-512] : bv[j-1024];
    return;
  }
  // GN partial stats
  __shared__ __align__(16) float red[8];
  const int idx = bx - 513;                 // 0..255
  const int grp = idx >> 2, chunk = idx & 3;
  const float* px = x + (size_t)grp*65536 + chunk*16384;
  float s = 0.f, ss = 0.f;
  for (int off = t*4; off < 16384; off += 1024){
    float4 u = *(const float4*)(px + off);
    s  += u.x + u.y + u.z + u.w;
    ss += u.x*u.x + u.y*u.y + u.z*u.z + u.w*u.w;
  }
  s = wsum(s); ss = wsum(ss);
  if ((t & 63) == 0){ red[t>>6] = s; red[4+(t>>6)] = ss; }
  __syncthreads();
  if (t == 0){
    psum2[(grp*4 + chunk)*2]     = red[0]+red[1]+red[2]+red[3];
    psum2[(grp*4 + chunk)*2 + 1] = red[4]+red[5]+red[6]+red[7];
  }
}

// ------- sum 4 bf16 partials, normalize by per-row sum of the 64 psum slices -------
__global__ __launch_bounds__(256) void reduce4_k(const u16* __restrict__ part,
                 const float* __restrict__ psum, u16* __restrict__ dst){
  __shared__ float invsh[4];
  const int t = threadIdx.x, w = t>>6, ln = t&63;
  const int row = blockIdx.x*4 + w;
  float s = psum[ln*8192 + blockIdx.y*4096 + row];
  s = wsum(s);
  if (ln == 0) invsh[w] = 1.f / s;
  __syncthreads();
  const int i = (blockIdx.x*256 + t)*8;
  const u16* p = part + (size_t)blockIdx.y*8388608;
  float a[8] = {};
  #pragma unroll
  for (int ks = 0; ks < 4; ++ks){
    ushort8 u = *(const ushort8*)(p + (size_t)ks*2097152 + i);
    #pragma unroll
    for (int j = 0; j < 8; ++j) a[j] += bf2f(u[j]);
  }
  const float iv = invsh[w];
  ushort8 o;
  #pragma unroll
  for (int j = 0; j < 8; ++j) o[j] = f2bf(a[j] * iv);
  *(ushort8*)(dst + (size_t)blockIdx.y*2097152 + i) = o;
}

// ---------------- GN apply (combines the 4 stat-partials per group in-block) ----------------
__global__ __launch_bounds__(256) void gn_apply_k(const float* __restrict__ x, const float* __restrict__ gamma,
                 const float* __restrict__ beta, const float* __restrict__ psum2, u16* __restrict__ ht){
  __shared__ __align__(16) u16 tile[32*512];
  __shared__ float gstat[64];   // [32 groups][mean,rstd] for this batch
  const int b = blockIdx.y, n0 = blockIdx.x*32, t = threadIdx.x;
  if (t < 32){
    const float* pp = psum2 + ((b*32 + t)*4)*2;
    float S1 = pp[0]+pp[2]+pp[4]+pp[6];
    float S2 = pp[1]+pp[3]+pp[5]+pp[7];
    float mean = S1 * (1.f/65536.f);
    float var  = S2 * (1.f/65536.f) - mean*mean;
    gstat[t*2]   = mean;
    gstat[t*2+1] = rsqrtf(var + 1e-6f);
  }
  __syncthreads();
  #pragma unroll
  for (int it = 0; it < 8; ++it){
    int c  = it*64 + (t>>2);
    int nn = (t&3)*8;
    const float* px = x + ((size_t)(b*512 + c) << 12) + n0 + nn;
    float4 u0 = *(const float4*)(px);
    float4 u1 = *(const float4*)(px + 4);
    float mean = gstat[(c>>4)*2];
    float rstd = gstat[(c>>4)*2 + 1];
    float ga = gamma[c], be = beta[c];
    float f[8] = {u0.x,u0.y,u0.z,u0.w,u1.x,u1.y,u1.z,u1.w};
    #pragma unroll
    for (int j = 0; j < 8; ++j)
      tile[(nn+j)*512 + c] = f2bf((f[j] - mean) * rstd * ga + be);
  }
  __syncthreads();
  const int rw = t>>3, sg = t&7;
  #pragma unroll
  for (int uu = 0; uu < 8; ++uu){
    ushort8 v = *(const ushort8*)(tile + rw*512 + sg*64 + uu*8);
    *(ushort8*)(ht + ((size_t)(b*4096 + n0 + rw) << 9) + sg*64 + uu*8) = v;
  }
}

// ============ 256x256 NT GEMM, BK=32 ring-2, 64KB LDS ============
// One {vmcnt(0); barrier} per K-step-32; compiler interleaves reads/stages/MFMA.
// EXPSUM: epilogue stores exp(acc); per-wave 64-col row sums -> psum (deterministic).
template<bool EXPSUM>
__global__ __launch_bounds__(512) void gemm8_nt(
    const u16* __restrict__ A, const u16* __restrict__ Bt, u16* __restrict__ C,
    float* __restrict__ psum,
    int K, int lda, int ldb, int ldc, int zdiv,
    long long aStrB, long long aStr, long long bStrB, long long bStr,
    long long cStrB, long long cStr)
{
  extern __shared__ __align__(16) char smem[];   // 65536 B: A[2][16K] | B[2][16K]
  const int z = blockIdx.z, z1 = z / zdiv, z2 = z % zdiv;
  A  += (size_t)aStrB*z1 + (size_t)aStr*z2;
  Bt += (size_t)bStrB*z1 + (size_t)bStr*z2;
  C  += (size_t)cStrB*z1 + (size_t)cStr*z2;
  const int nwg = gridDim.x*gridDim.y;
  int wg = blockIdx.y*gridDim.x + blockIdx.x;
  wg = (wg & 7)*(nwg >> 3) + (wg >> 3);
  const int m0 = (wg / gridDim.x)*256, n0 = (wg % gridDim.x)*256;

  const int t = threadIdx.x, wv = t>>6, ln = t&63;
  const int wm = wv>>2, wn = wv&3;
  const int lq = ln&15, lg = ln>>4;
  const int srow = ln>>2;
  const int sseg = (((ln&3) ^ ((srow>>1)&3)))*8;   // swizzled source seg (per-lane const)
  const int rslot = (lg ^ ((lq>>1)&3))*16;         // swizzled read slot (per-lane const)

  auto STAGE_A = [&](int u){
    char* base = smem + (u&1)*16384 + wv*1024;
    const u16* g = A + (size_t)(m0 + wv*16 + srow)*lda + u*32 + sseg;
    gl_lds16(g, base);
    gl_lds16(g + (size_t)128*lda, base + 8192);
  };
  auto STAGE_B = [&](int u){
    char* base = smem + 32768 + (u&1)*16384 + wv*1024;
    const u16* g = Bt + (size_t)(n0 + wv*16 + srow)*ldb + u*32 + sseg;
    gl_lds16(g, base);
    gl_lds16(g + (size_t)128*ldb, base + 8192);
  };
  auto LDA4 = [&](int u, int mh, bf16x8* a){
    const char* p = smem + (u&1)*16384 + (wm*128 + mh*64 + lq)*64 + rslot;
    #pragma unroll
    for (int i = 0; i < 4; ++i) a[i] = *(const bf16x8*)(p + i*1024);
  };
  auto LDB4 = [&](int u, bf16x8* b){
    const char* p = smem + 32768 + (u&1)*16384 + (wn*64 + lq)*64 + rslot;
    #pragma unroll
    for (int j = 0; j < 4; ++j) b[j] = *(const bf16x8*)(p + j*1024);
  };

  f32x4 acc[8][4] = {};
  auto MFMA16 = [&](bf16x8* a4, bf16x8* b4, int moff){
    __builtin_amdgcn_s_setprio(1);
    #pragma unroll
    for (int n = 0; n < 4; ++n)
      #pragma unroll
      for (int m = 0; m < 4; ++m)
        acc[moff+m][n] = __builtin_amdgcn_mfma_f32_16x16x32_bf16(a4[m], b4[n], acc[moff+m][n], 0, 0, 0);
    __builtin_amdgcn_s_setprio(0);
  };

  STAGE_A(0); STAGE_B(0);
  const int U = K >> 5;
  for (int u = 0; u < U; ++u){
    wait_vmcnt<0>();
    hard_barrier();
    bf16x8 a0[4], a1[4], b[4];
    LDA4(u, 0, a0); LDB4(u, b);
    if (u + 1 < U){ STAGE_A(u+1); STAGE_B(u+1); }
    MFMA16(a0, b, 0);
    LDA4(u, 1, a1);
    MFMA16(a1, b, 4);
  }
  // epilogue: C/D layout col=lane&15, row=(lane>>4)*4+reg
  const int slice = EXPSUM ? ((n0 >> 8)*4 + wn) : 0;
  #pragma unroll
  for (int m = 0; m < 8; ++m)
    #pragma unroll
    for (int r2 = 0; r2 < 4; ++r2){
      const int mg = m0 + wm*128 + m*16 + lg*4 + r2;
      u16* cp = C + (size_t)mg*ldc + n0 + wn*64 + lq;
      if constexpr (EXPSUM){
        float e[4], rs = 0.f;
        #pragma unroll
        for (int n = 0; n < 4; ++n){ e[n] = __expf(acc[m][n][r2]); rs += e[n]; }
        rs += __shfl_xor(rs, 1, 64);
        rs += __shfl_xor(rs, 2, 64);
        rs += __shfl_xor(rs, 4, 64);
        rs += __shfl_xor(rs, 8, 64);
        if (lq == 0) psum[slice*8192 + z1*4096 + mg] = rs;
        #pragma unroll
        for (int n = 0; n < 4; ++n) cp[n*16] = f2bf(e[n]);
      } else {
        #pragma unroll
        for (int n = 0; n < 4; ++n) cp[n*16] = f2bf(acc[m][n][r2]);
      }
    }
}

// ------- fused Q/K/V projection: grid (32,4,6), z = mat*2 + batch -------
__global__ __launch_bounds__(256) void qkv_k(
    const u16* __restrict__ Wstk, const u16* __restrict__ ht,
    const float* __restrict__ biases, u16* __restrict__ dstBase)
{
  __shared__ __align__(16) char smem[32768];
  char* smA0 = smem;
  char* smA1 = smem + 8192;
  char* smB0 = smem + 16384;
  char* smB1 = smem + 24576;
  const int z = blockIdx.z, mat = z >> 1, b = z & 1;
  const u16* A  = Wstk + mat*262144;
  const u16* Bt = ht + (size_t)b*2097152;
  const float* bias = biases + mat*512;
  const float oscale = (mat == 0) ? 0.044194173824159216f : 1.0f;
  u16* dst = dstBase + (size_t)mat*4194304 + (size_t)b*2097152;
  const int m0 = blockIdx.y*128, n0 = blockIdx.x*128;
  const int t = threadIdx.x, wv = t>>6, ln = t&63;
  const int wm = wv>>1, wn = wv&1;
  const int lq = ln&15, lg = ln>>4;
  const int srow = ln>>2;
  const int sseg = (((ln&3) ^ ((srow>>1)&3)))*8;
  const int rslot = (lg ^ ((lq>>1)&3))*16;
  f32x4 acc[4][4] = {};
  for (int kk = 0; kk < 512; kk += 64){
    __syncthreads();
    #pragma unroll
    for (int r = 0; r < 2; ++r){
      const int rr = r*64 + wv*16;
      const u16* pa = A  + (size_t)(m0 + rr + srow)*512 + kk + sseg;
      const u16* pb = Bt + (size_t)(n0 + rr + srow)*512 + kk + sseg;
      gl_lds16(pa,      smA0 + rr*64);
      gl_lds16(pa + 32, smA1 + rr*64);
      gl_lds16(pb,      smB0 + rr*64);
      gl_lds16(pb + 32, smB1 + rr*64);
    }
    __syncthreads();
    #pragma unroll
    for (int half = 0; half < 2; ++half){
      const char* pA = half ? smA1 : smA0;
      const char* pB = half ? smB1 : smB0;
      bf16x8 af[4], bfv[4];
      #pragma unroll
      for (int i = 0; i < 4; ++i) af[i]  = *(const bf16x8*)(pA + ((wm*64 + i*16 + lq)<<6) + rslot);
      #pragma unroll
      for (int j = 0; j < 4; ++j) bfv[j] = *(const bf16x8*)(pB + ((wn*64 + j*16 + lq)<<6) + rslot);
      #pragma unroll
      for (int i = 0; i < 4; ++i)
        #pragma unroll
        for (int j = 0; j < 4; ++j)
          acc[i][j] = __builtin_amdgcn_mfma_f32_16x16x32_bf16(af[i], bfv[j], acc[i][j], 0, 0, 0);
    }
  }
  if (mat == 2){          // V: direct C[m][n], ldc=4096
    #pragma unroll
    for (int i = 0; i < 4; ++i)
      #pragma unroll
      for (int r2 = 0; r2 < 4; ++r2){
        const int mg = m0 + wm*64 + i*16 + lg*4 + r2;
        float bv = bias[mg];
        #pragma unroll
        for (int j = 0; j < 4; ++j){
          const int ng = n0 + wn*64 + j*16 + lq;
          dst[(size_t)mg*4096 + ng] = f2bf(acc[i][j][r2] + bv);
        }
      }
  } else {                // Q/K: transposed C^T[n][m], ldc=512
    __syncthreads();
    u16* ct = (u16*)smem;  // [128 n][128 m]
    #pragma unroll
    for (int i = 0; i < 4; ++i)
      #pragma unroll
      for (int j = 0; j < 4; ++j)
        #pragma unroll
        for (int r2 = 0; r2 < 4; ++r2){
          const int ml = wm*64 + i*16 + lg*4 + r2;
          const int nl = wn*64 + j*16 + lq;
          ct[nl*128 + ml] = f2bf((acc[i][j][r2] + bias[m0 + ml]) * oscale);
        }
    __syncthreads();
    const int rw = t>>1, hf = (t&1)*64;
    #pragma unroll
    for (int u = 0; u < 8; ++u){
      *(ushort8*)(dst + (size_t)(n0 + rw)*512 + m0 + hf + u*8) =
          *(const ushort8*)(ct + rw*128 + hf + u*8);
    }
  }
}

// ---------------- 128x128 NT GEMM (final projection) ----------------
template<bool TRANS_OUT, bool HAS_BIAS, bool HAS_RES, bool F32OUT>
__global__ __launch_bounds__(256) void gemm_nt(
    const u16* __restrict__ A, const u16* __restrict__ Bt,
    const float* __restrict__ bias, const float* __restrict__ res, void* __restrict__ Cw_,
    int K, int lda, int ldb, int ldc, int zdiv,
    long long aStrB, long long aStr, long long bStrB, long long bStr,
    long long cStrB, long long cStr, long long rStrB, float oscale)
{
  __shared__ __align__(16) char smem[32768];
  char* smA0 = smem;
  char* smA1 = smem + 8192;
  char* smB0 = smem + 16384;
  char* smB1 = smem + 24576;
  const int z = blockIdx.z;
  const int z1 = z / zdiv, z2 = z % zdiv;
  A  += (size_t)aStrB*z1 + (size_t)aStr*z2;
  Bt += (size_t)bStrB*z1 + (size_t)bStr*z2;
  u16*   Cw16 = (u16*)Cw_   + (size_t)cStrB*z1 + (size_t)cStr*z2;
  float* Cw32 = (float*)Cw_ + (size_t)cStrB*z1 + (size_t)cStr*z2;
  const float* resp = HAS_RES ? (res + (size_t)rStrB*z1) : nullptr;
  const int m0 = blockIdx.y*128, n0 = blockIdx.x*128;
  const int t = threadIdx.x, wv = t>>6, ln = t&63;
  const int wm = wv>>1, wn = wv&1;
  const int lq = ln&15, lg = ln>>4;
  const int srow = ln>>2;
  const int sseg = (((ln&3) ^ ((srow>>1)&3)))*8;
  const int rslot = (lg ^ ((lq>>1)&3))*16;
  f32x4 acc[4][4] = {};
  for (int kk = 0; kk < K; kk += 64){
    __syncthreads();
    #pragma unroll
    for (int r = 0; r < 2; ++r){
      const int rr = r*64 + wv*16;
      const u16* pa = A  + (size_t)(m0 + rr + srow)*lda + kk + sseg;
      const u16* pb = Bt + (size_t)(n0 + rr + srow)*ldb + kk + sseg;
      gl_lds16(pa,      smA0 + rr*64);
      gl_lds16(pa + 32, smA1 + rr*64);
      gl_lds16(pb,      smB0 + rr*64);
      gl_lds16(pb + 32, smB1 + rr*64);
    }
    __syncthreads();
    #pragma unroll
    for (int half = 0; half < 2; ++half){
      const char* pA = half ? smA1 : smA0;
      const char* pB = half ? smB1 : smB0;
      bf16x8 af[4], bfv[4];
      #pragma unroll
      for (int i = 0; i < 4; ++i) af[i]  = *(const bf16x8*)(pA + ((wm*64 + i*16 + lq)<<6) + rslot);
      #pragma unroll
      for (int j = 0; j < 4; ++j) bfv[j] = *(const bf16x8*)(pB + ((wn*64 + j*16 + lq)<<6) + rslot);
      #pragma unroll
      for (int i = 0; i < 4; ++i)
        #pragma unroll
        for (int j = 0; j < 4; ++j)
          acc[i][j] = __builtin_amdgcn_mfma_f32_16x16x32_bf16(af[i], bfv[j], acc[i][j], 0, 0, 0);
    }
  }
  if constexpr (!TRANS_OUT){
    #pragma unroll
    for (int i = 0; i < 4; ++i){
      #pragma unroll
      for (int r2 = 0; r2 < 4; ++r2){
        const int mg = m0 + wm*64 + i*16 + lg*4 + r2;
        float bv = HAS_BIAS ? bias[mg] : 0.f;
        #pragma unroll
        for (int j = 0; j < 4; ++j){
          const int ng = n0 + wn*64 + j*16 + lq;
          float v = (acc[i][j][r2] + bv) * oscale;
          if (HAS_RES) v += resp[(size_t)mg*ldc + ng];
          if constexpr (F32OUT) Cw32[(size_t)mg*ldc + ng] = v;
          else                  Cw16[(size_t)mg*ldc + ng] = f2bf(v);
        }
      }
    }
  } else {
    __syncthreads();
    u16* ct = (u16*)smem;
    #pragma unroll
    for (int i = 0; i < 4; ++i)
      #pragma unroll
      for (int j = 0; j < 4; ++j)
        #pragma unroll
        for (int r2 = 0; r2 < 4; ++r2){
          const int ml = wm*64 + i*16 + lg*4 + r2;
          const int nl = wn*64 + j*16 + lq;
          float v = acc[i][j][r2];
          if (HAS_BIAS) v += bias[m0 + ml];
          ct[nl*128 + ml] = f2bf(v * oscale);
        }
    __syncthreads();
    const int rw = t>>1, hf = (t&1)*64;
    #pragma unroll
    for (int u = 0; u < 8; ++u){
      *(ushort8*)(Cw16 + (size_t)(n0 + rw)*ldc + m0 + hf + u*8) =
          *(const ushort8*)(ct + rw*128 + hf + u*8);
    }
  }
}

// ---------------- launch ----------------
extern "C" void kernel_launch(void* const* d_in, const int* in_sizes, int n_in,
                              void* d_out, int out_size, void* d_ws, size_t ws_size,
                              hipStream_t stream)
{
  const float* x   = (const float*)d_in[0];
  const float* gam = (const float*)d_in[1];
  const float* bet = (const float*)d_in[2];
  const float* wq  = (const float*)d_in[3];
  const float* bq  = (const float*)d_in[4];
  const float* wk  = (const float*)d_in[5];
  const float* bk  = (const float*)d_in[6];
  const float* wvp = (const float*)d_in[7];
  const float* bv  = (const float*)d_in[8];
  const float* wo  = (const float*)d_in[9];
  const float* bo  = (const float*)d_in[10];
  float* out = (float*)d_out;

  // ws layout: psum2 2KB | psum 2MB @4K | biasQKV | W bf16 x4 @4M | Qt|Kt|Vb|attT | Sbuf 64MB | part 32MB
  char* w = (char*)d_ws;
  float* psum2   = (float*)w;                  // [64][4][2] f32
  float* psum    = (float*)(w + 4096);         // [64][8192] f32
  float* biasQKV = (float*)(w + 2134016);
  u16* wqb  = (u16*)(w + (size_t)4194304);
  u16* wob  = wqb + 3*262144;
  u16* Qt   = wqb + 4*262144;
  u16* Kt   = Qt + 4194304;
  u16* Vb   = Kt + 4194304;
  u16* attT = Vb + 4194304;
  u16* Sbuf = attT + 4194304;
  u16* part = Sbuf + 33554432;
  u16* ht   = (u16*)d_out;   // GN output lives in d_out until qkv done

  const long long NC = 4096LL*512, NN = 4096LL*4096;

  // weights convert + biases + GN partial stats, one dispatch
  prep_k<<<dim3(769), dim3(256), 0, stream>>>(wq, wk, wvp, wo, bq, bk, bv, x, wqb, biasQKV, psum2);
  gn_apply_k<<<dim3(128,2), dim3(256), 0, stream>>>(x, gam, bet, psum2, ht);
  // fused Q/K/V projections (Qt pre-scaled by 512^-0.5)
  qkv_k<<<dim3(32,4,6), dim3(256), 0, stream>>>(wqb, ht, biasQKV, Qt);
  // expS[b][nq][nk] = exp(sum_c Qt[nq][c]*Kt[nk][c]); row partials -> psum
  gemm8_nt<true><<<dim3(16,16,2), dim3(512), 65536, stream>>>(
      Qt, Kt, Sbuf, psum, 512, 512, 512, 4096, 1, NC, 0, NC, 0, NN, 0);
  // split-K PV (4-way) on unnormalized expS
  gemm8_nt<false><<<dim3(2,16,8), dim3(512), 65536, stream>>>(
      Sbuf, Vb, part, nullptr, 1024, 4096, 4096, 512, 4,
      NN, 1024, NC, 1024, 8388608, 2097152);
  // sum partials + normalize (inv computed in-kernel from psum)
  reduce4_k<<<dim3(1024,2), dim3(256), 0, stream>>>(part, psum, attT);
  // out = x + (Wo att + bo)
  gemm_nt<false, true, true, true><<<dim3(32,4,2), dim3(256), 0, stream>>>(
      wob, attT, bo, x, out, 512, 512, 512, 4096, 1, 0,0, NC,0, NC,0, NC, 1.0f);
}